// Round 13
// baseline (170.969 us; speedup 1.0000x reference)
//
#include <hip/hip_runtime.h>
#include <hip/hip_bf16.h>

#define EMB 768
#define NH 8
#define DH 96
#define BATCH 8
#define SEQ 1024
#define M_TOT (BATCH * SEQ)   // 8192 rows of x
#define NCOLS (3 * EMB)       // q(768) | k(768) | v(768) output channels

typedef float f32x4 __attribute__((ext_vector_type(4)));
typedef __bf16 bf16x8 __attribute__((ext_vector_type(8)));

__device__ __forceinline__ unsigned short f2bf_bits(float f) {
  __hip_bfloat16 b = __float2bfloat16(f);
  return *reinterpret_cast<unsigned short*>(&b);
}

__device__ __forceinline__ void gload_lds16(const void* g, void* l) {
  // async global->LDS, 16B per lane; LDS dest is wave-uniform base (+lane*16 by HW)
  __builtin_amdgcn_global_load_lds(
      (__attribute__((address_space(1))) void*)(g),
      (__attribute__((address_space(3))) void*)(l), 16, 0, 0);
}

// ---------------- fused prep: x fp32->bf16  +  permuted weights/bias ----------------
#define PREPX_BLOCKS (M_TOT * EMB / 4 / 256)   // 6144
#define PREPW_BLOCKS (NCOLS * EMB / 256)       // 6912
__global__ void prep_kernel(const float* __restrict__ x, __hip_bfloat16* __restrict__ xb,
                            const float* __restrict__ qkv_w, const float* __restrict__ qkv_b,
                            const float* __restrict__ val_w, const float* __restrict__ val_b,
                            __hip_bfloat16* __restrict__ Wall, float* __restrict__ bias) {
  const int bid = blockIdx.x;
  if (bid < PREPX_BLOCKS) {
    int i = bid * 256 + threadIdx.x;
    f32x4 v = reinterpret_cast<const f32x4*>(x)[i];
    ushort4 o;
    o.x = f2bf_bits(v[0]);
    o.y = f2bf_bits(v[1]);
    o.z = f2bf_bits(v[2]);
    o.w = f2bf_bits(v[3]);
    reinterpret_cast<ushort4*>(xb)[i] = o;
  } else {
    const float inv_s = 0.03608439182435161f;  // 1/sqrt(768)
    int idx = (bid - PREPX_BLOCKS) * 256 + threadIdx.x;
    int r = idx / EMB;
    int c = idx - r * EMB;
    float v;
    if (r < EMB) {
      int h = r / DH, d = r - h * DH;
      int src = h * 192 + 2 * d;
      v = qkv_w[(size_t)src * EMB + c] * inv_s;
      if (c == 0) bias[r] = qkv_b[src] * inv_s;
    } else if (r < 2 * EMB) {
      int r2 = r - EMB;
      int h = r2 / DH, d = r2 - h * DH;
      int src = h * 192 + 2 * d + 1;
      v = qkv_w[(size_t)src * EMB + c];
      if (c == 0) bias[r] = qkv_b[src];
    } else {
      int r3 = r - 2 * EMB;
      v = val_w[(size_t)r3 * EMB + c];
      if (c == 0) bias[r] = val_b[r3];
    }
    Wall[idx] = __float2bfloat16(v);
  }
}

// ---------------- fused projection GEMM (m97-structure, 128x128, BK=32) ----------------
// 1-D grid 1152, XCD-chunked decode: flat = a + 8b + 144c -> m-tile = a*8+c, n-tile = b.
// The 18 blocks sharing an A-panel (same m-tile group, all n-tiles) are congruent mod 8
// -> same XCD -> A-panel stays in that XCD's L2 (18x reuse, ~8x less L3->L2 A traffic).
// q/k tiles: acc -> LDS (bf16) -> coalesced head-packed store. v tile: fp32 nt stores
// (write-once; keep L2/L3 for the attn working set).
__global__ __launch_bounds__(256) void gemm_kernel(
    const __hip_bfloat16* __restrict__ xb, const __hip_bfloat16* __restrict__ Wall,
    const float* __restrict__ bias, __hip_bfloat16* __restrict__ qhead,
    __hip_bfloat16* __restrict__ khead, float* __restrict__ vout) {
  __shared__ __hip_bfloat16 As[128 * 32];
  __shared__ __hip_bfloat16 Bs[128 * 32];
  __shared__ __hip_bfloat16 Cs[128][136];  // +8 pad, rows 16B-aligned
  const int tid = threadIdx.x;
  const int w = tid >> 6, l = tid & 63;
  const int flat = blockIdx.x;
  const int a_ = flat & 7;
  const int tq = flat >> 3;
  const int b_ = tq % 18;
  const int c_ = tq / 18;
  const int m0 = (a_ * 8 + c_) * 128;
  const int n0 = b_ * 128;
  const int wr = w >> 1, wc = w & 1;

  f32x4 acc[4][4] = {};

  const int sr0 = (w * 2 + 0) * 16 + (l >> 2);
  const int sr1 = (w * 2 + 1) * 16 + (l >> 2);
  const int sc = (l & 3) * 8;

  for (int kt = 0; kt < EMB / 32; ++kt) {
    const int k0 = kt * 32;
    gload_lds16(xb + (size_t)(m0 + sr0) * EMB + k0 + sc, (void*)(As + (w * 2 + 0) * 512));
    gload_lds16(xb + (size_t)(m0 + sr1) * EMB + k0 + sc, (void*)(As + (w * 2 + 1) * 512));
    gload_lds16(Wall + (size_t)(n0 + sr0) * EMB + k0 + sc, (void*)(Bs + (w * 2 + 0) * 512));
    gload_lds16(Wall + (size_t)(n0 + sr1) * EMB + k0 + sc, (void*)(Bs + (w * 2 + 1) * 512));
    __syncthreads();

    bf16x8 af[4], bfr[4];
#pragma unroll
    for (int t = 0; t < 4; ++t) {
      af[t] = *reinterpret_cast<const bf16x8*>(As + (wr * 64 + t * 16 + (l & 15)) * 32 + (l >> 4) * 8);
      bfr[t] = *reinterpret_cast<const bf16x8*>(Bs + (wc * 64 + t * 16 + (l & 15)) * 32 + (l >> 4) * 8);
    }
#pragma unroll
    for (int i = 0; i < 4; ++i)
#pragma unroll
      for (int j = 0; j < 4; ++j)
        acc[i][j] = __builtin_amdgcn_mfma_f32_16x16x32_bf16(af[i], bfr[j], acc[i][j], 0, 0, 0);
    __syncthreads();
  }

  if (n0 >= 2 * EMB) {
    const int rowbase = m0 + wr * 64;
    const int colbase = n0 - 2 * EMB + wc * 64;
#pragma unroll
    for (int j = 0; j < 4; ++j) {
      const int n = colbase + j * 16 + (l & 15);
      const float bb = bias[2 * EMB + n];
#pragma unroll
      for (int i = 0; i < 4; ++i) {
#pragma unroll
        for (int q = 0; q < 4; ++q) {
          const int m = rowbase + i * 16 + (l >> 4) * 4 + q;
          __builtin_nontemporal_store(acc[i][j][q] + bb, &vout[(size_t)m * EMB + n]);
        }
      }
    }
  } else {
#pragma unroll
    for (int j = 0; j < 4; ++j) {
      const int nl = wc * 64 + j * 16 + (l & 15);
      const float bb = bias[n0 + nl];
#pragma unroll
      for (int i = 0; i < 4; ++i) {
#pragma unroll
        for (int q = 0; q < 4; ++q) {
          const int ml = wr * 64 + i * 16 + (l >> 4) * 4 + q;
          Cs[ml][nl] = __float2bfloat16(acc[i][j][q] + bb);
        }
      }
    }
    __syncthreads();
    __hip_bfloat16* dst = (n0 >= EMB) ? khead : qhead;
    const int ch0 = (n0 >= EMB) ? (n0 - EMB) : n0;
    const int cg = (tid & 15) * 8;
    const int gch = ch0 + cg;
    const int hh = gch / DH, dd = gch - hh * DH;
#pragma unroll
    for (int pass = 0; pass < 8; ++pass) {
      const int r = pass * 16 + (tid >> 4);
      const int m = m0 + r;
      const int bb_ = m >> 10, mm = m & 1023;
      bf16x8 v8 = *reinterpret_cast<const bf16x8*>(&Cs[r][cg]);
      *reinterpret_cast<bf16x8*>(dst + ((size_t)(bb_ * NH + hh) * SEQ + mm) * DH + dd) = v8;
    }
  }
}

// ---------------- fused QK^T + softmax: byte-exact r11 (best known: ~105 us) ----------------
// Grid 4096 (8 b-variants sharing rel rows co-XCD). 512 thr = 8 waves; block = 16 rows
// x 1024 cols; wave w owns contiguous cols [w*128, +128) -> stores form 512B runs.
// Energy stored non-temporal. K staged per-wave ring-3, counted vmcnt(6/3/0).
__global__ __launch_bounds__(512, 2) void attn_kernel(
    const __hip_bfloat16* __restrict__ qhead, const __hip_bfloat16* __restrict__ khead,
    const float* __restrict__ rel, float* __restrict__ eout) {
  __shared__ alignas(16) char KS[8 * 3 * 3072];  // 73728 B: 8 waves x ring of 3
  __shared__ float redm[16][8];
  __shared__ float reds[16][8];

  const int t = threadIdx.x;
  const int w = t >> 6, l = t & 63;
  const int lr = l >> 4, lc = l & 15;
  const int flat = blockIdx.x;
  const int u = flat >> 6;
  const int b = (flat >> 3) & 7;
  const int g = u * 8 + (flat & 7);
  const int h = g >> 6;
  const int rb = g & 63;
  const int row0 = rb * 16;
  const size_t bh = (size_t)(b * NH + h);

  const __hip_bfloat16* qsrc = qhead + (bh * SEQ + row0 + lc) * DH;
  bf16x8 qf[3];
#pragma unroll
  for (int kc = 0; kc < 3; ++kc)
    qf[kc] = *reinterpret_cast<const bf16x8*>(qsrc + kc * 32 + lr * 8);

  const float* relsrc = rel + ((size_t)h * SEQ + row0 + lc) * SEQ + w * 128 + lr * 4;
  f32x4 relv[8];
#pragma unroll
  for (int s = 0; s < 8; ++s)
    relv[s] = *reinterpret_cast<const f32x4*>(relsrc + s * 16);

  const __hip_bfloat16* ksrc = khead + bh * SEQ * DH + (size_t)w * 128 * DH;
  char* kdst = KS + w * 9216;

#define STAGE_K(s, buf)                                                             \
  {                                                                                 \
    const __hip_bfloat16* s_ = ksrc + (size_t)(s) * 1536 + (size_t)l * 8;           \
    gload_lds16(s_, kdst + (buf) * 3072);                                           \
    gload_lds16(s_ + 512, kdst + (buf) * 3072 + 1024);                              \
    gload_lds16(s_ + 1024, kdst + (buf) * 3072 + 2048);                             \
  }

  STAGE_K(0, 0)
  STAGE_K(1, 1)

  f32x4 acc[8];
#pragma unroll
  for (int s = 0; s < 8; ++s) {
    if (s < 6) STAGE_K(s + 2, (s + 2) % 3)
    if (s < 6) {
      asm volatile("s_waitcnt vmcnt(6)" ::: "memory");
    } else if (s == 6) {
      asm volatile("s_waitcnt vmcnt(3)" ::: "memory");
    } else {
      asm volatile("s_waitcnt vmcnt(0)" ::: "memory");
    }
    __builtin_amdgcn_sched_barrier(0);
    const __hip_bfloat16* kp =
        reinterpret_cast<const __hip_bfloat16*>(kdst + (s % 3) * 3072) + lc * DH;
    f32x4 a = {0.f, 0.f, 0.f, 0.f};
    __builtin_amdgcn_s_setprio(1);
#pragma unroll
    for (int kc = 0; kc < 3; ++kc) {
      bf16x8 kf = *reinterpret_cast<const bf16x8*>(kp + kc * 32 + lr * 8);
      a = __builtin_amdgcn_mfma_f32_16x16x32_bf16(kf, qf[kc], a, 0, 0, 0);
    }
    __builtin_amdgcn_s_setprio(0);
    acc[s] = a + relv[s];
  }
#undef STAGE_K

  float mx = -3.4e38f;
#pragma unroll
  for (int s = 0; s < 8; ++s)
    mx = fmaxf(mx, fmaxf(fmaxf(acc[s][0], acc[s][1]), fmaxf(acc[s][2], acc[s][3])));
  mx = fmaxf(mx, __shfl_xor(mx, 16));
  mx = fmaxf(mx, __shfl_xor(mx, 32));
  if (l < 16) redm[lc][w] = mx;
  __syncthreads();
  float M = redm[lc][0];
#pragma unroll
  for (int i = 1; i < 8; ++i) M = fmaxf(M, redm[lc][i]);

  float sm = 0.f;
#pragma unroll
  for (int s = 0; s < 8; ++s) {
#pragma unroll
    for (int j = 0; j < 4; ++j) {
      float e = __expf(acc[s][j] - M);
      acc[s][j] = e;
      sm += e;
    }
  }
  sm += __shfl_xor(sm, 16);
  sm += __shfl_xor(sm, 32);
  if (l < 16) reds[lc][w] = sm;
  __syncthreads();
  float S = 0.f;
#pragma unroll
  for (int i = 0; i < 8; ++i) S += reds[lc][i];
  const float rinv = 1.0f / S;

  float* op = eout + (bh * SEQ + row0 + lc) * SEQ + w * 128 + lr * 4;
#pragma unroll
  for (int s = 0; s < 8; ++s) {
    f32x4 v = acc[s] * rinv;
    __builtin_nontemporal_store(v, reinterpret_cast<f32x4*>(op + s * 16));
  }
}

extern "C" void kernel_launch(void* const* d_in, const int* in_sizes, int n_in,
                              void* d_out, int out_size, void* d_ws, size_t ws_size,
                              hipStream_t stream) {
  const float* x = (const float*)d_in[0];
  const float* rel = (const float*)d_in[1];
  const float* qkv_w = (const float*)d_in[2];
  const float* qkv_b = (const float*)d_in[3];
  const float* val_w = (const float*)d_in[4];
  const float* val_b = (const float*)d_in[5];
  float* out = (float*)d_out;

  char* ws = (char*)d_ws;
  __hip_bfloat16* xb = (__hip_bfloat16*)(ws);                  // 12,582,912
  __hip_bfloat16* Wall = (__hip_bfloat16*)(ws + 12582912);     //  3,538,944
  float* bias = (float*)(ws + 16121856);                       //      9,216
  __hip_bfloat16* qhead = (__hip_bfloat16*)(ws + 16131072);    // 12,582,912  [b][h][n][96]
  __hip_bfloat16* khead = (__hip_bfloat16*)(ws + 28713984);    // 12,582,912  [b][h][n][96]

  float* vout = out;                       // [8192][768] values
  float* eout = out + (size_t)M_TOT * EMB; // [64][1024][1024] energy

  prep_kernel<<<dim3(PREPX_BLOCKS + PREPW_BLOCKS), dim3(256), 0, stream>>>(
      x, xb, qkv_w, qkv_b, val_w, val_b, Wall, bias);
  gemm_kernel<<<dim3(M_TOT / 128 * (NCOLS / 128)), dim3(256), 0, stream>>>(xb, Wall, bias,
                                                                           qhead, khead, vout);
  attn_kernel<<<dim3(SEQ / 16 * NH * BATCH), dim3(512), 0, stream>>>(qhead, khead, rel, eout);
}

// Round 14
// 162.850 us; speedup vs baseline: 1.0499x; 1.0499x over previous
//
#include <hip/hip_runtime.h>
#include <hip/hip_bf16.h>

#define EMB 768
#define NH 8
#define DH 96
#define BATCH 8
#define SEQ 1024
#define M_TOT (BATCH * SEQ)   // 8192 rows of x
#define NCOLS (3 * EMB)       // q(768) | k(768) | v(768) output channels

typedef float f32x4 __attribute__((ext_vector_type(4)));
typedef __bf16 bf16x8 __attribute__((ext_vector_type(8)));

__device__ __forceinline__ unsigned short f2bf_bits(float f) {
  __hip_bfloat16 b = __float2bfloat16(f);
  return *reinterpret_cast<unsigned short*>(&b);
}

__device__ __forceinline__ void gload_lds16(const void* g, void* l) {
  // async global->LDS, 16B per lane; LDS dest is wave-uniform base (+lane*16 by HW)
  __builtin_amdgcn_global_load_lds(
      (__attribute__((address_space(1))) void*)(g),
      (__attribute__((address_space(3))) void*)(l), 16, 0, 0);
}

// ---------------- prep: x fp32 -> bf16 ----------------
__global__ void prep_x_kernel(const float* __restrict__ x, __hip_bfloat16* __restrict__ xb) {
  const int n4 = M_TOT * EMB / 4;
  int i = blockIdx.x * blockDim.x + threadIdx.x;
  if (i < n4) {
    f32x4 v = reinterpret_cast<const f32x4*>(x)[i];
    ushort4 o;
    o.x = f2bf_bits(v[0]);
    o.y = f2bf_bits(v[1]);
    o.z = f2bf_bits(v[2]);
    o.w = f2bf_bits(v[3]);
    reinterpret_cast<ushort4*>(xb)[i] = o;
  }
}

// ---------------- prep: permuted weights -> bf16, bias fp32 ----------------
__global__ void prep_w_kernel(const float* __restrict__ qkv_w, const float* __restrict__ qkv_b,
                              const float* __restrict__ val_w, const float* __restrict__ val_b,
                              __hip_bfloat16* __restrict__ Wall, float* __restrict__ bias) {
  const float inv_s = 0.03608439182435161f;  // 1/sqrt(768)
  int idx = blockIdx.x * 256 + threadIdx.x;
  if (idx >= NCOLS * EMB) return;
  int r = idx / EMB;
  int c = idx - r * EMB;
  float v;
  if (r < EMB) {
    int h = r / DH, d = r - h * DH;
    int src = h * 192 + 2 * d;
    v = qkv_w[(size_t)src * EMB + c] * inv_s;
    if (c == 0) bias[r] = qkv_b[src] * inv_s;
  } else if (r < 2 * EMB) {
    int r2 = r - EMB;
    int h = r2 / DH, d = r2 - h * DH;
    int src = h * 192 + 2 * d + 1;
    v = qkv_w[(size_t)src * EMB + c];
    if (c == 0) bias[r] = qkv_b[src];
  } else {
    int r3 = r - 2 * EMB;
    v = val_w[(size_t)r3 * EMB + c];
    if (c == 0) bias[r] = val_b[r3];
  }
  Wall[idx] = __float2bfloat16(v);
}

// ---------------- fused projection GEMM (m97-structure, 128x128, BK=32) ----------------
// Byte-identical to r11 (2D grid, plain stores; q/k via padded-LDS head-packed epilogue).
__global__ __launch_bounds__(256) void gemm_kernel(
    const __hip_bfloat16* __restrict__ xb, const __hip_bfloat16* __restrict__ Wall,
    const float* __restrict__ bias, __hip_bfloat16* __restrict__ qhead,
    __hip_bfloat16* __restrict__ khead, float* __restrict__ vout) {
  __shared__ __hip_bfloat16 As[128 * 32];
  __shared__ __hip_bfloat16 Bs[128 * 32];
  __shared__ __hip_bfloat16 Cs[128][136];  // +8 pad, rows 16B-aligned
  const int tid = threadIdx.x;
  const int w = tid >> 6, l = tid & 63;
  const int m0 = blockIdx.x * 128;
  const int n0 = blockIdx.y * 128;
  const int wr = w >> 1, wc = w & 1;

  f32x4 acc[4][4] = {};

  const int sr0 = (w * 2 + 0) * 16 + (l >> 2);
  const int sr1 = (w * 2 + 1) * 16 + (l >> 2);
  const int sc = (l & 3) * 8;

  for (int kt = 0; kt < EMB / 32; ++kt) {
    const int k0 = kt * 32;
    gload_lds16(xb + (size_t)(m0 + sr0) * EMB + k0 + sc, (void*)(As + (w * 2 + 0) * 512));
    gload_lds16(xb + (size_t)(m0 + sr1) * EMB + k0 + sc, (void*)(As + (w * 2 + 1) * 512));
    gload_lds16(Wall + (size_t)(n0 + sr0) * EMB + k0 + sc, (void*)(Bs + (w * 2 + 0) * 512));
    gload_lds16(Wall + (size_t)(n0 + sr1) * EMB + k0 + sc, (void*)(Bs + (w * 2 + 1) * 512));
    __syncthreads();

    bf16x8 af[4], bfr[4];
#pragma unroll
    for (int t = 0; t < 4; ++t) {
      af[t] = *reinterpret_cast<const bf16x8*>(As + (wr * 64 + t * 16 + (l & 15)) * 32 + (l >> 4) * 8);
      bfr[t] = *reinterpret_cast<const bf16x8*>(Bs + (wc * 64 + t * 16 + (l & 15)) * 32 + (l >> 4) * 8);
    }
#pragma unroll
    for (int i = 0; i < 4; ++i)
#pragma unroll
      for (int j = 0; j < 4; ++j)
        acc[i][j] = __builtin_amdgcn_mfma_f32_16x16x32_bf16(af[i], bfr[j], acc[i][j], 0, 0, 0);
    __syncthreads();
  }

  if (n0 >= 2 * EMB) {
    const int rowbase = m0 + wr * 64;
    const int colbase = n0 - 2 * EMB + wc * 64;
#pragma unroll
    for (int j = 0; j < 4; ++j) {
      const int n = colbase + j * 16 + (l & 15);
      const float bb = bias[2 * EMB + n];
#pragma unroll
      for (int i = 0; i < 4; ++i) {
#pragma unroll
        for (int q = 0; q < 4; ++q) {
          const int m = rowbase + i * 16 + (l >> 4) * 4 + q;
          vout[(size_t)m * EMB + n] = acc[i][j][q] + bb;
        }
      }
    }
  } else {
#pragma unroll
    for (int j = 0; j < 4; ++j) {
      const int nl = wc * 64 + j * 16 + (l & 15);
      const float bb = bias[n0 + nl];
#pragma unroll
      for (int i = 0; i < 4; ++i) {
#pragma unroll
        for (int q = 0; q < 4; ++q) {
          const int ml = wr * 64 + i * 16 + (l >> 4) * 4 + q;
          Cs[ml][nl] = __float2bfloat16(acc[i][j][q] + bb);
        }
      }
    }
    __syncthreads();
    __hip_bfloat16* dst = (n0 >= EMB) ? khead : qhead;
    const int ch0 = (n0 >= EMB) ? (n0 - EMB) : n0;
    const int cg = (tid & 15) * 8;
    const int gch = ch0 + cg;
    const int hh = gch / DH, dd = gch - hh * DH;
#pragma unroll
    for (int pass = 0; pass < 8; ++pass) {
      const int r = pass * 16 + (tid >> 4);
      const int m = m0 + r;
      const int bb_ = m >> 10, mm = m & 1023;
      bf16x8 v8 = *reinterpret_cast<const bf16x8*>(&Cs[r][cg]);
      *reinterpret_cast<bf16x8*>(dst + ((size_t)(bb_ * NH + hh) * SEQ + mm) * DH + dd) = v8;
    }
  }
}

// ---------------- fused QK^T + softmax: r11 + rotation-swizzled K-LDS ----------------
// Identical to r11 except the K chunk layout in LDS: LDS position (row r, slot p)
// holds source granule (r, (p - r) mod 12) -- a per-row rotation (bijective).
// Staging keeps linear LDS dest + coalesced 192B-row global source (permuted within
// each row); reads fetch slot (kc*4+lr+lc) mod 12, spreading the 16 lc-lanes across
// banks: 8-way ds_read_b128 conflict (48*lc mod 32 = {0,16}) -> ~2-3-way (~free).
__global__ __launch_bounds__(512, 2) void attn_kernel(
    const __hip_bfloat16* __restrict__ qhead, const __hip_bfloat16* __restrict__ khead,
    const float* __restrict__ rel, float* __restrict__ eout) {
  __shared__ alignas(16) char KS[8 * 3 * 3072];  // 73728 B: 8 waves x ring of 3
  __shared__ float redm[16][8];
  __shared__ float reds[16][8];

  const int t = threadIdx.x;
  const int w = t >> 6, l = t & 63;
  const int lr = l >> 4, lc = l & 15;
  const int flat = blockIdx.x;
  const int u = flat >> 6;
  const int b = (flat >> 3) & 7;
  const int g = u * 8 + (flat & 7);
  const int h = g >> 6;
  const int rb = g & 63;
  const int row0 = rb * 16;
  const size_t bh = (size_t)(b * NH + h);

  const __hip_bfloat16* qsrc = qhead + (bh * SEQ + row0 + lc) * DH;
  bf16x8 qf[3];
#pragma unroll
  for (int kc = 0; kc < 3; ++kc)
    qf[kc] = *reinterpret_cast<const bf16x8*>(qsrc + kc * 32 + lr * 8);

  const float* relsrc = rel + ((size_t)h * SEQ + row0 + lc) * SEQ + w * 128 + lr * 4;
  f32x4 relv[8];
#pragma unroll
  for (int s = 0; s < 8; ++s)
    relv[s] = *reinterpret_cast<const f32x4*>(relsrc + s * 16);

  const __hip_bfloat16* ksrc = khead + bh * SEQ * DH + (size_t)w * 128 * DH;
  char* kdst = KS + w * 9216;

  // per-lane swizzled source offsets (elements): LDS linear index G = j*64 + l
  // -> LDS position (rr = G/12, pp = G%12) -> source granule (rr, (pp-rr) mod 12)
  int srcoff[3];
#pragma unroll
  for (int j = 0; j < 3; ++j) {
    const int G = j * 64 + l;
    const int rr = G / 12;
    const int pp = G - rr * 12;
    const int ss = (pp - rr + 24) % 12;
    srcoff[j] = rr * DH + ss * 8;
  }
  // per-lane swizzled read offsets (bytes within chunk buffer)
  int rdoff[3];
#pragma unroll
  for (int kc = 0; kc < 3; ++kc)
    rdoff[kc] = lc * 192 + ((kc * 4 + lr + lc) % 12) * 16;

#define STAGE_K(s, buf)                                                             \
  {                                                                                 \
    const __hip_bfloat16* s_ = ksrc + (size_t)(s) * 1536;                           \
    gload_lds16(s_ + srcoff[0], kdst + (buf) * 3072);                               \
    gload_lds16(s_ + srcoff[1], kdst + (buf) * 3072 + 1024);                        \
    gload_lds16(s_ + srcoff[2], kdst + (buf) * 3072 + 2048);                        \
  }

  STAGE_K(0, 0)
  STAGE_K(1, 1)

  f32x4 acc[8];
#pragma unroll
  for (int s = 0; s < 8; ++s) {
    if (s < 6) STAGE_K(s + 2, (s + 2) % 3)
    if (s < 6) {
      asm volatile("s_waitcnt vmcnt(6)" ::: "memory");
    } else if (s == 6) {
      asm volatile("s_waitcnt vmcnt(3)" ::: "memory");
    } else {
      asm volatile("s_waitcnt vmcnt(0)" ::: "memory");
    }
    __builtin_amdgcn_sched_barrier(0);
    const char* kp = kdst + (s % 3) * 3072;
    f32x4 a = {0.f, 0.f, 0.f, 0.f};
    __builtin_amdgcn_s_setprio(1);
#pragma unroll
    for (int kc = 0; kc < 3; ++kc) {
      bf16x8 kf = *reinterpret_cast<const bf16x8*>(kp + rdoff[kc]);
      a = __builtin_amdgcn_mfma_f32_16x16x32_bf16(kf, qf[kc], a, 0, 0, 0);
    }
    __builtin_amdgcn_s_setprio(0);
    acc[s] = a + relv[s];
  }
#undef STAGE_K

  float mx = -3.4e38f;
#pragma unroll
  for (int s = 0; s < 8; ++s)
    mx = fmaxf(mx, fmaxf(fmaxf(acc[s][0], acc[s][1]), fmaxf(acc[s][2], acc[s][3])));
  mx = fmaxf(mx, __shfl_xor(mx, 16));
  mx = fmaxf(mx, __shfl_xor(mx, 32));
  if (l < 16) redm[lc][w] = mx;
  __syncthreads();
  float M = redm[lc][0];
#pragma unroll
  for (int i = 1; i < 8; ++i) M = fmaxf(M, redm[lc][i]);

  float sm = 0.f;
#pragma unroll
  for (int s = 0; s < 8; ++s) {
#pragma unroll
    for (int j = 0; j < 4; ++j) {
      float e = __expf(acc[s][j] - M);
      acc[s][j] = e;
      sm += e;
    }
  }
  sm += __shfl_xor(sm, 16);
  sm += __shfl_xor(sm, 32);
  if (l < 16) reds[lc][w] = sm;
  __syncthreads();
  float S = 0.f;
#pragma unroll
  for (int i = 0; i < 8; ++i) S += reds[lc][i];
  const float rinv = 1.0f / S;

  float* op = eout + (bh * SEQ + row0 + lc) * SEQ + w * 128 + lr * 4;
#pragma unroll
  for (int s = 0; s < 8; ++s) {
    f32x4 v = acc[s] * rinv;
    __builtin_nontemporal_store(v, reinterpret_cast<f32x4*>(op + s * 16));
  }
}

extern "C" void kernel_launch(void* const* d_in, const int* in_sizes, int n_in,
                              void* d_out, int out_size, void* d_ws, size_t ws_size,
                              hipStream_t stream) {
  const float* x = (const float*)d_in[0];
  const float* rel = (const float*)d_in[1];
  const float* qkv_w = (const float*)d_in[2];
  const float* qkv_b = (const float*)d_in[3];
  const float* val_w = (const float*)d_in[4];
  const float* val_b = (const float*)d_in[5];
  float* out = (float*)d_out;

  char* ws = (char*)d_ws;
  __hip_bfloat16* xb = (__hip_bfloat16*)(ws);                  // 12,582,912
  __hip_bfloat16* Wall = (__hip_bfloat16*)(ws + 12582912);     //  3,538,944
  float* bias = (float*)(ws + 16121856);                       //      9,216
  __hip_bfloat16* qhead = (__hip_bfloat16*)(ws + 16131072);    // 12,582,912  [b][h][n][96]
  __hip_bfloat16* khead = (__hip_bfloat16*)(ws + 28713984);    // 12,582,912  [b][h][n][96]

  float* vout = out;                       // [8192][768] values
  float* eout = out + (size_t)M_TOT * EMB; // [64][1024][1024] energy

  prep_x_kernel<<<dim3(M_TOT * EMB / 4 / 256), dim3(256), 0, stream>>>(x, xb);
  prep_w_kernel<<<dim3(NCOLS * EMB / 256), dim3(256), 0, stream>>>(qkv_w, qkv_b, val_w, val_b,
                                                                   Wall, bias);
  gemm_kernel<<<dim3(M_TOT / 128, NCOLS / 128), dim3(256), 0, stream>>>(xb, Wall, bias, qhead,
                                                                        khead, vout);
  attn_kernel<<<dim3(SEQ / 16 * NH * BATCH), dim3(512), 0, stream>>>(qhead, khead, rel, eout);
}